// Round 7
// baseline (465.765 us; speedup 1.0000x reference)
//
#include <hip/hip_runtime.h>
#include <hip/hip_bf16.h>

typedef __bf16 bf16x8 __attribute__((ext_vector_type(8)));
typedef __bf16 bf16x4 __attribute__((ext_vector_type(4)));
typedef float  f32x4  __attribute__((ext_vector_type(4)));

#define MFMA16(a,b,c) __builtin_amdgcn_mfma_f32_16x16x32_bf16((a),(b),(c),0,0,0)

// Opaque pin: forces fragments to stay register-resident (not rematerializable).
#define PIN8(v8) do { f32x4 _t = __builtin_bit_cast(f32x4, (v8)); \
                      asm volatile("" : "+v"(_t)); \
                      (v8) = __builtin_bit_cast(bf16x8, _t); } while (0)

// LDS-only barrier: waits LDS ops (lgkmcnt) but leaves global prefetch vmcnt
// outstanding across the rendezvous (compiler inserts vmcnt wait at the use).
__device__ __forceinline__ void barrier_lds() {
  asm volatile("s_waitcnt lgkmcnt(0)\n\ts_barrier" ::: "memory");
}

constexpr int Bb = 2048, Tt = 80, Ee = 100, Uu = 256;
constexpr int BM = 8;          // batch rows per rnn block
constexpr int RNT = 512;       // rnn: 8 waves
constexpr int PGT = 512;       // pregemm: 8 waves
constexpr int HCH = 256;       // elems per k-chunk (32 k x 8 rows)
constexpr int HB = 8 * HCH;    // one h buffer

__device__ __forceinline__ float ldmix(const void* p, int i, bool isbf) {
  return isbf ? (float)((const __bf16*)p)[i] : ((const float*)p)[i];
}

__device__ __forceinline__ float fast_tanh(float x) {
  float e = __expf(2.f * x);
  return 1.f - 2.f / (e + 1.f);
}

__global__ void detect_kernel(const void* wh, int* flag) {
  __shared__ int cnt;
  if (threadIdx.x == 0) cnt = 0;
  __syncthreads();
  const unsigned short* u = (const unsigned short*)wh;
  int c = 0;
  for (int i = threadIdx.x; i < 256; i += 64) {
    unsigned short h = u[2 * i];
    int ex = (h >> 7) & 0xFF;
    if (ex >= 135 || (ex >= 1 && ex <= 95)) c++;
  }
  atomicAdd(&cnt, c);
  __syncthreads();
  if (threadIdx.x == 0) *flag = (cnt < 64) ? 1 : 0;
}

// ---------------- pre-GEMM (R3/R4 known-good, runtime dtype) ---------------
// U layout: U[t][rb][tid32][16] bf16; slot = e*4+i where (row = ((tid32>>4)&1)*4+i,
// col = (tid32>>5)*64 + e*16 + (tid32&15)); bias0 pre-folded.
__launch_bounds__(PGT, 1)
__global__ void pregemm_kernel(const int* __restrict__ tokens,
                               const void* __restrict__ emb,
                               const void* __restrict__ Wx0,
                               const void* __restrict__ bias,
                               __bf16* __restrict__ U,
                               const int* __restrict__ flag) {
  const bool isbf = (*flag != 0);
  __shared__ __align__(16) __bf16 sA[8 * 4 * 64 * 8];
  __shared__ __align__(16) __bf16 lout[32768];

  const int tid = threadIdx.x, lane = tid & 63, wv = tid >> 6;
  const int m = lane & 15, kc = lane >> 4;
  const int g = blockIdx.x / 10, tc = blockIdx.x % 10;
  const int B0 = g * 16, T0 = tc * 8;

  for (int q = tid; q < 128 * 32; q += PGT) {
    int r = q >> 5, c = (q & 31) * 4;
    int tok = tokens[(B0 + (r >> 3)) * Tt + T0 + (r & 7)];
    float v0 = 0.f, v1 = 0.f, v2 = 0.f, v3 = 0.f;
    if (c < Ee) {
      if (isbf) {
        bf16x4 t4 = *(const bf16x4*)((const __bf16*)emb + tok * Ee + c);
        v0 = (float)t4[0]; v1 = (float)t4[1]; v2 = (float)t4[2]; v3 = (float)t4[3];
      } else {
        f32x4 t4 = *(const f32x4*)((const float*)emb + tok * Ee + c);
        v0 = t4[0]; v1 = t4[1]; v2 = t4[2]; v3 = t4[3];
      }
    }
    __bf16* p = sA + (((r >> 4) * 4 + (c >> 5)) * 64 + ((c >> 3) & 3) * 16 + (r & 15)) * 8 + (c & 7);
    p[0] = (__bf16)v0; p[1] = (__bf16)v1; p[2] = (__bf16)v2; p[3] = (__bf16)v3;
  }

  bf16x8 fB[2][4];
  float bs[2];
  #pragma unroll
  for (int e = 0; e < 2; ++e) {
    const int col = wv * 32 + e * 16 + m;
    bs[e] = ldmix(bias, col, isbf);
    #pragma unroll
    for (int s = 0; s < 4; ++s) {
      bf16x8 tr;
      #pragma unroll
      for (int j = 0; j < 8; ++j) {
        int k = s * 32 + kc * 8 + j;
        tr[j] = (k < Ee) ? (__bf16)ldmix(Wx0, k * Uu + col, isbf) : (__bf16)0.f;
      }
      fB[e][s] = tr;
    }
  }
  __syncthreads();

  const int au = (kc * 16 + m) * 8;
  const int lr3 = lane >> 5;
  const int tb = ((lane >> 4) & 1) * 4;
  #pragma unroll
  for (int mt = 0; mt < 8; ++mt) {
    f32x4 a0 = {0.f,0.f,0.f,0.f}, a1 = {0.f,0.f,0.f,0.f};
    #pragma unroll
    for (int s = 0; s < 4; ++s) {
      bf16x8 a = *(const bf16x8*)(sA + (mt * 4 + s) * 512 + au);
      a0 = MFMA16(a, fB[0][s], a0);
      a1 = MFMA16(a, fB[1][s], a1);
    }
    int rr = mt * 2 + lr3;
    int rb_l = rr >> 3, r8 = rr & 7;
    int lane32 = ((r8 >> 2) << 4) + m;
    int i = r8 & 3;
    int e0 = (wv & 1) * 2;
    #pragma unroll
    for (int ii = 0; ii < 4; ++ii) {
      int base = (((tb + ii) * 2 + rb_l) * 128 + (wv >> 1) * 32 + lane32) * 16 + i;
      lout[base + e0 * 4]       = (__bf16)(a0[ii] + bs[0]);
      lout[base + (e0 + 1) * 4] = (__bf16)(a1[ii] + bs[1]);
    }
  }
  __syncthreads();

  for (int it = 0; it < 8; ++it) {
    int idx = (it * PGT + tid) * 8;
    int p = idx >> 11, w = idx & 2047;
    int t_l = p >> 1, rb_l = p & 1;
    size_t dst = ((size_t)((T0 + t_l) * 256 + (g * 2 + rb_l))) * 2048 + w;
    *(bf16x8*)(U + dst) = *(const bf16x8*)(lout + idx);
  }
}

// ---------------- persistent 2-layer RNN, fused single-barrier scan --------
// 8 waves x 2 col-tiles; weights pinned; LDS-only barrier keeps u-prefetch
// vmcnt outstanding across steps.
__launch_bounds__(RNT, 2)
__global__ void rnn_kernel(const void* __restrict__ Wx1,
                           const void* __restrict__ Wh,
                           const void* __restrict__ bias,
                           const void* __restrict__ h0g,
                           const void* __restrict__ Wo,
                           const void* __restrict__ bo,
                           const __bf16* __restrict__ U,
                           void* __restrict__ out,
                           const int* __restrict__ flag) {
  const bool isbf = (*flag != 0);

  __shared__ __align__(16) __bf16 s_h0[2 * HB];
  __shared__ __align__(16) __bf16 s_h1[2 * HB];

  const int tid = threadIdx.x, lane = tid & 63, wv = tid >> 6;  // wv 0..7
  const int m = lane & 15, kc = lane >> 4;
  const int rb = blockIdx.x, b0 = rb * BM;
  const int au = (kc * 8 + (m & 7)) * 8;   // A-read; lanes m>=8 broadcast row m-8

  for (int idx = tid; idx < BM * Uu; idx += RNT) {
    int r = idx >> 8, c = idx & 255;
    int off = (c >> 5) * HCH + (((c >> 3) & 3) * 8 + r) * 8 + (c & 7);
    s_h0[off] = (__bf16)ldmix(h0g, (b0 + r) * Uu + c, isbf);
    s_h1[off] = (__bf16)ldmix(h0g, Bb * Uu + (b0 + r) * Uu + c, isbf);
  }

  // persistent weight B-frags: 2 tiles x 3 matrices x 8 chunks = 192 regs
  bf16x8 fWh0[2][8], fWx1f[2][8], fWh1[2][8];
  float b1v[2];
  #pragma unroll
  for (int e = 0; e < 2; ++e) {
    const int col = wv * 32 + e * 16 + m;
    b1v[e] = ldmix(bias, Uu + col, isbf);
    #pragma unroll
    for (int s = 0; s < 8; ++s) {
      const int kb = s * 32 + kc * 8;
      bf16x8 t0, t1, t2;
      #pragma unroll
      for (int j = 0; j < 8; ++j) {
        t0[j] = (__bf16)ldmix(Wh,  (kb + j) * Uu + col, isbf);
        t1[j] = (__bf16)ldmix(Wx1, (kb + j) * Uu + col, isbf);
        t2[j] = (__bf16)ldmix(Wh,  Uu * Uu + (kb + j) * Uu + col, isbf);
      }
      fWh0[e][s] = t0; fWx1f[e][s] = t1; fWh1[e][s] = t2;
    }
  }
  #pragma unroll
  for (int e = 0; e < 2; ++e) {
    #pragma unroll
    for (int s = 0; s < 8; ++s) {
      PIN8(fWh0[e][s]); PIN8(fWx1f[e][s]); PIN8(fWh1[e][s]);
    }
  }

  // u fetch: lane needs old-layout tid32 = (wv>>1)*32 + (kc&1)*16 + m,
  // slots (wv&1)*8 .. +7 (one bf16x8 per lane)
  const int tid32u = (wv >> 1) * 32 + ((kc & 1) * 16) + m;
  const __bf16* Ubase = U + (size_t)tid32u * 16 + (wv & 1) * 8 + (size_t)rb * 2048;

  const int kc2 = m >> 3, j2 = m & 7, rb2 = (lane >> 4) * 4;  // write decomp (lane<32)

  bf16x8 u0 = *(const bf16x8*)(Ubase);   // u(0)

  __syncthreads();

  // ---- prologue: h0_new(0) = tanh(u(0) + h0_init@Wh0) -> s_h0[1] ----
  {
    f32x4 d0 = {(float)u0[0], (float)u0[1], (float)u0[2], (float)u0[3]};
    f32x4 d1 = {(float)u0[4], (float)u0[5], (float)u0[6], (float)u0[7]};
    const __bf16* hb = s_h0 + au;
    #pragma unroll
    for (int s = 0; s < 8; ++s) {
      bf16x8 a = *(const bf16x8*)(hb + s * HCH);
      d0 = MFMA16(a, fWh0[0][s], d0);
      d1 = MFMA16(a, fWh0[1][s], d1);
    }
    u0 = *(const bf16x8*)(Ubase + (size_t)1 * 256 * 2048);  // prefetch u(1)
    if (lane < 32) {
      #pragma unroll
      for (int e = 0; e < 2; ++e) {
        __bf16* wp = s_h0 + HB + wv * HCH + ((e * 2 + kc2) * 8 + rb2) * 8 + j2;
        f32x4& dd = e ? d1 : d0;
        #pragma unroll
        for (int ii = 0; ii < 4; ++ii)
          wp[ii * 8] = (__bf16)fast_tanh(dd[ii]);
      }
    }
    barrier_lds();
  }

  #pragma unroll 2
  for (int t = 0; t < Tt; ++t) {
    const int p = t & 1, pn = p ^ 1;
    int tf = (t + 2 < Tt) ? t + 2 : Tt - 1;
    bf16x8 un = *(const bf16x8*)(Ubase + (size_t)tf * 256 * 2048);

    // 6 chains: B=h0n@Wx1, C=h1@Wh1 (sum -> h1_new), D=u+h0n@Wh0 (-> h0_next)
    f32x4 cB0 = {0.f,0.f,0.f,0.f}, cB1 = {0.f,0.f,0.f,0.f};
    f32x4 cC0 = {0.f,0.f,0.f,0.f}, cC1 = {0.f,0.f,0.f,0.f};
    f32x4 cD0 = {(float)u0[0], (float)u0[1], (float)u0[2], (float)u0[3]};
    f32x4 cD1 = {(float)u0[4], (float)u0[5], (float)u0[6], (float)u0[7]};
    {
      const __bf16* h0b = s_h0 + pn * HB + au;   // h0_new(t)
      const __bf16* h1b = s_h1 + p * HB + au;    // h1(t)
      #pragma unroll
      for (int s = 0; s < 8; ++s) {
        bf16x8 a0 = *(const bf16x8*)(h0b + s * HCH);
        bf16x8 a1 = *(const bf16x8*)(h1b + s * HCH);
        cB0 = MFMA16(a0, fWx1f[0][s], cB0);
        cB1 = MFMA16(a0, fWx1f[1][s], cB1);
        cD0 = MFMA16(a0, fWh0[0][s], cD0);
        cD1 = MFMA16(a0, fWh0[1][s], cD1);
        cC0 = MFMA16(a1, fWh1[0][s], cC0);
        cC1 = MFMA16(a1, fWh1[1][s], cC1);
      }
    }
    if (lane < 32) {
      #pragma unroll
      for (int e = 0; e < 2; ++e) {
        const int toff = wv * HCH + ((e * 2 + kc2) * 8 + rb2) * 8 + j2;
        __bf16* wp1 = s_h1 + pn * HB + toff;     // h1_new(t)
        __bf16* wp0 = s_h0 + p * HB + toff;      // h0_new(t+1)
        f32x4 hb1, hd0;
        if (e) { hb1 = cB1 + cC1; hd0 = cD1; } else { hb1 = cB0 + cC0; hd0 = cD0; }
        #pragma unroll
        for (int ii = 0; ii < 4; ++ii) {
          wp1[ii * 8] = (__bf16)fast_tanh(hb1[ii] + b1v[e]);
          wp0[ii * 8] = (__bf16)fast_tanh(hd0[ii]);
        }
      }
    }
    u0 = un;
    barrier_lds();
  }

  // ---- epilogue: sigmoid(h1_new(79) @ Wo + bo); lives in s_h1[0] ----
  if (tid < 256) {
    const int r = tid >> 5, q = tid & 31;
    const __bf16* hp = s_h1 + (q >> 2) * HCH + ((q & 3) * 8 + r) * 8;
    bf16x8 hv = *(const bf16x8*)hp;
    float part = 0.f;
    #pragma unroll
    for (int j = 0; j < 8; ++j) part += (float)hv[j] * ldmix(Wo, q * 8 + j, isbf);
    #pragma unroll
    for (int o = 16; o >= 1; o >>= 1) part += __shfl_down(part, o, 32);
    if (q == 0) {
      float z = part + ldmix(bo, 0, isbf);
      float sg = 1.f / (1.f + __expf(-z));
      if (isbf) ((__bf16*)out)[b0 + r] = (__bf16)sg;
      else      ((float*)out)[b0 + r]  = sg;
    }
  }
}

extern "C" void kernel_launch(void* const* d_in, const int* in_sizes, int n_in,
                              void* d_out, int out_size, void* d_ws, size_t ws_size,
                              hipStream_t stream) {
  const int*  tokens = (const int*)d_in[0];
  const void* emb = d_in[1];
  const void* Wx0 = d_in[2];
  const void* Wx1 = d_in[3];
  const void* Wh  = d_in[4];
  const void* b   = d_in[5];
  const void* h0  = d_in[6];
  const void* Wo  = d_in[7];
  const void* bo  = d_in[8];

  int* flag = (int*)d_ws;
  __bf16* U = (__bf16*)((char*)d_ws + 256);
  const size_t needU = 256 + (size_t)Tt * 256 * 2048 * sizeof(__bf16);  // ~84 MB
  if (ws_size < needU) return;

  detect_kernel<<<1, 64, 0, stream>>>(Wh, flag);
  pregemm_kernel<<<dim3(128 * 10), dim3(PGT), 0, stream>>>(tokens, emb, Wx0, b, U, flag);
  rnn_kernel<<<dim3(Bb / BM), dim3(RNT), 0, stream>>>(Wx1, Wh, b, h0, Wo, bo, U, d_out, flag);
}

// Round 8
// 314.523 us; speedup vs baseline: 1.4809x; 1.4809x over previous
//
#include <hip/hip_runtime.h>
#include <hip/hip_bf16.h>

typedef __bf16 bf16x8 __attribute__((ext_vector_type(8)));
typedef __bf16 bf16x4 __attribute__((ext_vector_type(4)));
typedef float  f32x4  __attribute__((ext_vector_type(4)));

#define MFMA16(a,b,c) __builtin_amdgcn_mfma_f32_16x16x32_bf16((a),(b),(c),0,0,0)

// Opaque pin: forces the fragment to stay register-resident (asm outputs are
// not rematerializable, so the compiler cannot re-load weights per step).
#define PIN8(v8) do { f32x4 _t = __builtin_bit_cast(f32x4, (v8)); \
                      asm volatile("" : "+v"(_t)); \
                      (v8) = __builtin_bit_cast(bf16x8, _t); } while (0)

// LDS-only barrier: waits LDS ops (lgkmcnt) but leaves the global u-prefetch
// vmcnt outstanding across the rendezvous (use-site gets a precise vmcnt wait).
__device__ __forceinline__ void barrier_lds() {
  asm volatile("s_waitcnt lgkmcnt(0)\n\ts_barrier" ::: "memory");
}

constexpr int Bb = 2048, Tt = 80, Ee = 100, Uu = 256;
constexpr int BM = 8;          // batch rows per rnn block
constexpr int RNT = 512;       // rnn: 8 waves
constexpr int PGT = 512;       // pregemm: 8 waves
constexpr int HCH = 256;       // elems per k-chunk (32 k x 8 rows)
constexpr int HB = 8 * HCH;    // one h buffer

template<bool ISBF>
__device__ __forceinline__ float ldf(const void* p, int i) {
  if constexpr (ISBF) return (float)((const __bf16*)p)[i];
  else                return ((const float*)p)[i];
}

__device__ __forceinline__ float fast_tanh(float x) {
  float e = __expf(2.f * x);
  return 1.f - 2.f / (e + 1.f);
}

__global__ void detect_kernel(const void* wh, int* flag) {
  __shared__ int cnt;
  if (threadIdx.x == 0) cnt = 0;
  __syncthreads();
  const unsigned short* u = (const unsigned short*)wh;
  int c = 0;
  for (int i = threadIdx.x; i < 256; i += 64) {
    unsigned short h = u[2 * i];
    int ex = (h >> 7) & 0xFF;
    if (ex >= 135 || (ex >= 1 && ex <= 95)) c++;
  }
  atomicAdd(&cnt, c);
  __syncthreads();
  if (threadIdx.x == 0) *flag = (cnt < 64) ? 1 : 0;
}

// ---------------- pre-GEMM (R3/R4 known-good) ------------------------------
// U layout: U[t][rb][tid32][16] bf16; slot = e*4+i where (row = ((tid32>>4)&1)*4+i,
// col = (tid32>>5)*64 + e*16 + (tid32&15)); bias0 pre-folded.
template<bool ISBF>
__launch_bounds__(PGT, 1)
__global__ void pregemm_kernel(const int* __restrict__ tokens,
                               const void* __restrict__ emb,
                               const void* __restrict__ Wx0,
                               const void* __restrict__ bias,
                               __bf16* __restrict__ U,
                               const int* __restrict__ flag) {
  if ((*flag != 0) != ISBF) return;
  __shared__ __align__(16) __bf16 sA[8 * 4 * 64 * 8];
  __shared__ __align__(16) __bf16 lout[32768];

  const int tid = threadIdx.x, lane = tid & 63, wv = tid >> 6;
  const int m = lane & 15, kc = lane >> 4;
  const int g = blockIdx.x / 10, tc = blockIdx.x % 10;
  const int B0 = g * 16, T0 = tc * 8;

  for (int q = tid; q < 128 * 32; q += PGT) {
    int r = q >> 5, c = (q & 31) * 4;
    int tok = tokens[(B0 + (r >> 3)) * Tt + T0 + (r & 7)];
    float v0 = 0.f, v1 = 0.f, v2 = 0.f, v3 = 0.f;
    if (c < Ee) {
      if constexpr (ISBF) {
        bf16x4 t4 = *(const bf16x4*)((const __bf16*)emb + tok * Ee + c);
        v0 = (float)t4[0]; v1 = (float)t4[1]; v2 = (float)t4[2]; v3 = (float)t4[3];
      } else {
        f32x4 t4 = *(const f32x4*)((const float*)emb + tok * Ee + c);
        v0 = t4[0]; v1 = t4[1]; v2 = t4[2]; v3 = t4[3];
      }
    }
    __bf16* p = sA + (((r >> 4) * 4 + (c >> 5)) * 64 + ((c >> 3) & 3) * 16 + (r & 15)) * 8 + (c & 7);
    p[0] = (__bf16)v0; p[1] = (__bf16)v1; p[2] = (__bf16)v2; p[3] = (__bf16)v3;
  }

  bf16x8 fB[2][4];
  float bs[2];
  #pragma unroll
  for (int e = 0; e < 2; ++e) {
    const int col = wv * 32 + e * 16 + m;
    bs[e] = ldf<ISBF>(bias, col);
    #pragma unroll
    for (int s = 0; s < 4; ++s) {
      bf16x8 tr;
      #pragma unroll
      for (int j = 0; j < 8; ++j) {
        int k = s * 32 + kc * 8 + j;
        tr[j] = (k < Ee) ? (__bf16)ldf<ISBF>(Wx0, k * Uu + col) : (__bf16)0.f;
      }
      fB[e][s] = tr;
    }
  }
  __syncthreads();

  const int au = (kc * 16 + m) * 8;
  const int lr3 = lane >> 5;
  const int tb = ((lane >> 4) & 1) * 4;
  #pragma unroll
  for (int mt = 0; mt < 8; ++mt) {
    f32x4 a0 = {0.f,0.f,0.f,0.f}, a1 = {0.f,0.f,0.f,0.f};
    #pragma unroll
    for (int s = 0; s < 4; ++s) {
      bf16x8 a = *(const bf16x8*)(sA + (mt * 4 + s) * 512 + au);
      a0 = MFMA16(a, fB[0][s], a0);
      a1 = MFMA16(a, fB[1][s], a1);
    }
    int rr = mt * 2 + lr3;
    int rb_l = rr >> 3, r8 = rr & 7;
    int lane32 = ((r8 >> 2) << 4) + m;
    int i = r8 & 3;
    int e0 = (wv & 1) * 2;
    #pragma unroll
    for (int ii = 0; ii < 4; ++ii) {
      int base = (((tb + ii) * 2 + rb_l) * 128 + (wv >> 1) * 32 + lane32) * 16 + i;
      lout[base + e0 * 4]       = (__bf16)(a0[ii] + bs[0]);
      lout[base + (e0 + 1) * 4] = (__bf16)(a1[ii] + bs[1]);
    }
  }
  __syncthreads();

  for (int it = 0; it < 8; ++it) {
    int idx = (it * PGT + tid) * 8;
    int p = idx >> 11, w = idx & 2047;
    int t_l = p >> 1, rb_l = p & 1;
    size_t dst = ((size_t)((T0 + t_l) * 256 + (g * 2 + rb_l))) * 2048 + w;
    *(bf16x8*)(U + dst) = *(const bf16x8*)(lout + idx);
  }
}

// ---------------- persistent 2-layer RNN, fused single-barrier scan --------
// 8 waves x 2 col-tiles; weights pinned; LDS-only barrier in the K-loop.
template<bool ISBF>
__launch_bounds__(RNT, 2)
__global__ void rnn_kernel(const void* __restrict__ Wx1,
                           const void* __restrict__ Wh,
                           const void* __restrict__ bias,
                           const void* __restrict__ h0g,
                           const void* __restrict__ Wo,
                           const void* __restrict__ bo,
                           const __bf16* __restrict__ U,
                           void* __restrict__ out,
                           const int* __restrict__ flag) {
  if ((*flag != 0) != ISBF) return;

  __shared__ __align__(16) __bf16 s_h0[2 * HB];
  __shared__ __align__(16) __bf16 s_h1[2 * HB];

  const int tid = threadIdx.x, lane = tid & 63, wv = tid >> 6;  // wv 0..7
  const int m = lane & 15, kc = lane >> 4;
  const int rb = blockIdx.x, b0 = rb * BM;
  const int au = (kc * 8 + (m & 7)) * 8;   // A-read; lanes m>=8 broadcast row m-8

  for (int idx = tid; idx < BM * Uu; idx += RNT) {
    int r = idx >> 8, c = idx & 255;
    int off = (c >> 5) * HCH + (((c >> 3) & 3) * 8 + r) * 8 + (c & 7);
    s_h0[off] = (__bf16)ldf<ISBF>(h0g, (b0 + r) * Uu + c);
    s_h1[off] = (__bf16)ldf<ISBF>(h0g, Bb * Uu + (b0 + r) * Uu + c);
  }

  // persistent weight B-frags: 2 tiles x 3 matrices x 8 chunks = 192 regs
  bf16x8 fWh0[2][8], fWx1f[2][8], fWh1[2][8];
  float b1v[2];
  #pragma unroll
  for (int e = 0; e < 2; ++e) {
    const int col = wv * 32 + e * 16 + m;
    b1v[e] = ldf<ISBF>(bias, Uu + col);
    #pragma unroll
    for (int s = 0; s < 8; ++s) {
      const int kb = s * 32 + kc * 8;
      bf16x8 t0, t1, t2;
      #pragma unroll
      for (int j = 0; j < 8; ++j) {
        t0[j] = (__bf16)ldf<ISBF>(Wh,  (kb + j) * Uu + col);
        t1[j] = (__bf16)ldf<ISBF>(Wx1, (kb + j) * Uu + col);
        t2[j] = (__bf16)ldf<ISBF>(Wh,  Uu * Uu + (kb + j) * Uu + col);
      }
      fWh0[e][s] = t0; fWx1f[e][s] = t1; fWh1[e][s] = t2;
    }
  }
  #pragma unroll
  for (int e = 0; e < 2; ++e) {
    #pragma unroll
    for (int s = 0; s < 8; ++s) {
      PIN8(fWh0[e][s]); PIN8(fWx1f[e][s]); PIN8(fWh1[e][s]);
    }
  }

  // u fetch: lane needs old-layout tid32 = (wv>>1)*32 + (kc&1)*16 + m,
  // slots (wv&1)*8 .. +7 (one bf16x8 per lane)
  const int tid32u = (wv >> 1) * 32 + ((kc & 1) * 16) + m;
  const __bf16* Ubase = U + (size_t)tid32u * 16 + (wv & 1) * 8 + (size_t)rb * 2048;

  const int kc2 = m >> 3, j2 = m & 7, rb2 = (lane >> 4) * 4;  // write decomp (lane<32)

  bf16x8 u0 = *(const bf16x8*)(Ubase);   // u(0)

  __syncthreads();

  // ---- prologue: h0_new(0) = tanh(u(0) + h0_init@Wh0) -> s_h0[1] ----
  {
    f32x4 d0 = {(float)u0[0], (float)u0[1], (float)u0[2], (float)u0[3]};
    f32x4 d1 = {(float)u0[4], (float)u0[5], (float)u0[6], (float)u0[7]};
    const __bf16* hb = s_h0 + au;
    #pragma unroll
    for (int s = 0; s < 8; ++s) {
      bf16x8 a = *(const bf16x8*)(hb + s * HCH);
      d0 = MFMA16(a, fWh0[0][s], d0);
      d1 = MFMA16(a, fWh0[1][s], d1);
    }
    u0 = *(const bf16x8*)(Ubase + (size_t)1 * 256 * 2048);  // prefetch u(1)
    if (lane < 32) {
      #pragma unroll
      for (int e = 0; e < 2; ++e) {
        __bf16* wp = s_h0 + HB + wv * HCH + ((e * 2 + kc2) * 8 + rb2) * 8 + j2;
        f32x4& dd = e ? d1 : d0;
        #pragma unroll
        for (int ii = 0; ii < 4; ++ii)
          wp[ii * 8] = (__bf16)fast_tanh(dd[ii]);
      }
    }
    barrier_lds();
  }

  for (int t = 0; t < Tt; ++t) {
    const int p = t & 1, pn = p ^ 1;
    int tf = (t + 2 < Tt) ? t + 2 : Tt - 1;
    bf16x8 un = *(const bf16x8*)(Ubase + (size_t)tf * 256 * 2048);

    // 6 chains: B=h0n@Wx1, C=h1@Wh1 (sum -> h1_new), D=u+h0n@Wh0 (-> h0_next)
    f32x4 cB0 = {0.f,0.f,0.f,0.f}, cB1 = {0.f,0.f,0.f,0.f};
    f32x4 cC0 = {0.f,0.f,0.f,0.f}, cC1 = {0.f,0.f,0.f,0.f};
    f32x4 cD0 = {(float)u0[0], (float)u0[1], (float)u0[2], (float)u0[3]};
    f32x4 cD1 = {(float)u0[4], (float)u0[5], (float)u0[6], (float)u0[7]};
    {
      const __bf16* h0b = s_h0 + pn * HB + au;   // h0_new(t)
      const __bf16* h1b = s_h1 + p * HB + au;    // h1(t)
      #pragma unroll
      for (int s = 0; s < 8; ++s) {
        bf16x8 a0 = *(const bf16x8*)(h0b + s * HCH);
        bf16x8 a1 = *(const bf16x8*)(h1b + s * HCH);
        cB0 = MFMA16(a0, fWx1f[0][s], cB0);
        cB1 = MFMA16(a0, fWx1f[1][s], cB1);
        cD0 = MFMA16(a0, fWh0[0][s], cD0);
        cD1 = MFMA16(a0, fWh0[1][s], cD1);
        cC0 = MFMA16(a1, fWh1[0][s], cC0);
        cC1 = MFMA16(a1, fWh1[1][s], cC1);
      }
    }
    if (lane < 32) {
      #pragma unroll
      for (int e = 0; e < 2; ++e) {
        const int toff = wv * HCH + ((e * 2 + kc2) * 8 + rb2) * 8 + j2;
        __bf16* wp1 = s_h1 + pn * HB + toff;     // h1_new(t)
        __bf16* wp0 = s_h0 + p * HB + toff;      // h0_new(t+1)
        f32x4 hb1, hd0;
        if (e) { hb1 = cB1 + cC1; hd0 = cD1; } else { hb1 = cB0 + cC0; hd0 = cD0; }
        #pragma unroll
        for (int ii = 0; ii < 4; ++ii) {
          wp1[ii * 8] = (__bf16)fast_tanh(hb1[ii] + b1v[e]);
          wp0[ii * 8] = (__bf16)fast_tanh(hd0[ii]);
        }
      }
    }
    u0 = un;
    barrier_lds();
  }

  // ---- epilogue: sigmoid(h1_new(79) @ Wo + bo); lives in s_h1[0] ----
  if (tid < 256) {
    const int r = tid >> 5, q = tid & 31;
    const __bf16* hp = s_h1 + (q >> 2) * HCH + ((q & 3) * 8 + r) * 8;
    bf16x8 hv = *(const bf16x8*)hp;
    float part = 0.f;
    #pragma unroll
    for (int j = 0; j < 8; ++j) part += (float)hv[j] * ldf<ISBF>(Wo, q * 8 + j);
    #pragma unroll
    for (int o = 16; o >= 1; o >>= 1) part += __shfl_down(part, o, 32);
    if (q == 0) {
      float z = part + ldf<ISBF>(bo, 0);
      float sg = 1.f / (1.f + __expf(-z));
      if constexpr (ISBF) ((__bf16*)out)[b0 + r] = (__bf16)sg;
      else                ((float*)out)[b0 + r]  = sg;
    }
  }
}

extern "C" void kernel_launch(void* const* d_in, const int* in_sizes, int n_in,
                              void* d_out, int out_size, void* d_ws, size_t ws_size,
                              hipStream_t stream) {
  const int*  tokens = (const int*)d_in[0];
  const void* emb = d_in[1];
  const void* Wx0 = d_in[2];
  const void* Wx1 = d_in[3];
  const void* Wh  = d_in[4];
  const void* b   = d_in[5];
  const void* h0  = d_in[6];
  const void* Wo  = d_in[7];
  const void* bo  = d_in[8];

  int* flag = (int*)d_ws;
  __bf16* U = (__bf16*)((char*)d_ws + 256);
  const size_t needU = 256 + (size_t)Tt * 256 * 2048 * sizeof(__bf16);  // ~84 MB
  if (ws_size < needU) return;

  detect_kernel<<<1, 64, 0, stream>>>(Wh, flag);
  pregemm_kernel<true ><<<dim3(128 * 10), dim3(PGT), 0, stream>>>(tokens, emb, Wx0, b, U, flag);
  pregemm_kernel<false><<<dim3(128 * 10), dim3(PGT), 0, stream>>>(tokens, emb, Wx0, b, U, flag);
  rnn_kernel<true ><<<dim3(Bb / BM), dim3(RNT), 0, stream>>>(Wx1, Wh, b, h0, Wo, bo, U, d_out, flag);
  rnn_kernel<false><<<dim3(Bb / BM), dim3(RNT), 0, stream>>>(Wx1, Wh, b, h0, Wo, bo, U, d_out, flag);
}

// Round 9
// 306.567 us; speedup vs baseline: 1.5193x; 1.0259x over previous
//
#include <hip/hip_runtime.h>
#include <hip/hip_bf16.h>

typedef __bf16 bf16x8 __attribute__((ext_vector_type(8)));
typedef __bf16 bf16x4 __attribute__((ext_vector_type(4)));
typedef float  f32x4  __attribute__((ext_vector_type(4)));

#define MFMA16(a,b,c) __builtin_amdgcn_mfma_f32_16x16x32_bf16((a),(b),(c),0,0,0)

// Opaque pin: forces the fragment to stay register-resident (asm outputs are
// not rematerializable, so the compiler cannot re-load weights per step).
#define PIN8(v8) do { f32x4 _t = __builtin_bit_cast(f32x4, (v8)); \
                      asm volatile("" : "+v"(_t)); \
                      (v8) = __builtin_bit_cast(bf16x8, _t); } while (0)

// LDS-only barrier: waits LDS ops but leaves global prefetch vmcnt outstanding.
__device__ __forceinline__ void barrier_lds() {
  asm volatile("s_waitcnt lgkmcnt(0)\n\ts_barrier" ::: "memory");
}

constexpr int Bb = 2048, Tt = 80, Ee = 100, Uu = 256;
constexpr int BM = 8;          // batch rows per rnn block
constexpr int RNT = 512;       // rnn: 8 waves
constexpr int HCH = 256;       // elems per k-chunk (32 k x 8 rows)
constexpr int HB = 8 * HCH;    // one h buffer

template<bool ISBF>
__device__ __forceinline__ float ldf(const void* p, int i) {
  if constexpr (ISBF) return (float)((const __bf16*)p)[i];
  else                return ((const float*)p)[i];
}

__device__ __forceinline__ float fast_tanh(float x) {
  float e = __expf(2.f * x);
  return 1.f - 2.f / (e + 1.f);
}

__global__ void detect_kernel(const void* wh, int* flag) {
  __shared__ int cnt;
  if (threadIdx.x == 0) cnt = 0;
  __syncthreads();
  const unsigned short* u = (const unsigned short*)wh;
  int c = 0;
  for (int i = threadIdx.x; i < 256; i += 64) {
    unsigned short h = u[2 * i];
    int ex = (h >> 7) & 0xFF;
    if (ex >= 135 || (ex >= 1 && ex <= 95)) c++;
  }
  atomicAdd(&cnt, c);
  __syncthreads();
  if (threadIdx.x == 0) *flag = (cnt < 64) ? 1 : 0;
}

// ---------------- persistent 2-layer RNN with fused U-production -----------
// Prologue: block computes U[t][rb][tid32][16] (bias0 folded) for its own 8
// rows via direct per-lane A-frag gather from emb + per-lane b128 stores
// (producer lane == consumer lane for its slot-half; verified index algebra).
// Scan: identical to R8 (8 waves x 2 col-tiles, pinned weights, 1 barrier).
template<bool ISBF>
__launch_bounds__(RNT, 2)
__global__ void rnn_kernel(const int* __restrict__ tokens,
                           const void* __restrict__ emb,
                           const void* __restrict__ Wx0,
                           const void* __restrict__ Wx1,
                           const void* __restrict__ Wh,
                           const void* __restrict__ bias,
                           const void* __restrict__ h0g,
                           const void* __restrict__ Wo,
                           const void* __restrict__ bo,
                           __bf16* __restrict__ U,
                           void* __restrict__ out,
                           const int* __restrict__ flag) {
  if ((*flag != 0) != ISBF) return;

  __shared__ __align__(16) __bf16 s_h0[2 * HB];
  __shared__ __align__(16) __bf16 s_h1[2 * HB];

  const int tid = threadIdx.x, lane = tid & 63, wv = tid >> 6;  // wv 0..7
  const int m = lane & 15, kc = lane >> 4;
  const int rb = blockIdx.x, b0 = rb * BM;
  const int au = (kc * 8 + (m & 7)) * 8;   // A-read; lanes m>=8 broadcast row m-8

  for (int idx = tid; idx < BM * Uu; idx += RNT) {
    int r = idx >> 8, c = idx & 255;
    int off = (c >> 5) * HCH + (((c >> 3) & 3) * 8 + r) * 8 + (c & 7);
    s_h0[off] = (__bf16)ldf<ISBF>(h0g, (b0 + r) * Uu + c);
    s_h1[off] = (__bf16)ldf<ISBF>(h0g, Bb * Uu + (b0 + r) * Uu + c);
  }

  // ---- fused pre-GEMM: U slice for this block's 8 rows, all 80 t ----------
  {
    bf16x8 fX[2][4];            // Wx0 B-frags (2 e-tiles x 4 k-chunks)
    float b0v[2];
    #pragma unroll
    for (int e = 0; e < 2; ++e) {
      const int col = wv * 32 + e * 16 + m;
      b0v[e] = ldf<ISBF>(bias, col);
      #pragma unroll
      for (int s = 0; s < 4; ++s) {
        bf16x8 tr;
        #pragma unroll
        for (int j = 0; j < 8; ++j) {
          int k = s * 32 + kc * 8 + j;
          tr[j] = (k < Ee) ? (__bf16)ldf<ISBF>(Wx0, k * Uu + col) : (__bf16)0.f;
        }
        fX[e][s] = tr;
      }
    }
    // q = row-group role of lane>>4 on the C side; same physical reg as kc.
    const int tid32p = (wv >> 1) * 32 + ((kc & 1) * 16) + m;
    __bf16* Ustore = U + (size_t)tid32p * 16 + (wv & 1) * 8;
    for (int tc = 0; tc < 10; ++tc) {
      const int T0 = tc * 8;
      #pragma unroll
      for (int mt = 0; mt < 4; ++mt) {
        // A-frag gather: tile row = m; t = T0 + mt*2 + (m>>3); b = b0 + (m&7)
        const int tok = tokens[(b0 + (m & 7)) * Tt + T0 + mt * 2 + (m >> 3)];
        f32x4 a0 = {b0v[0], b0v[0], b0v[0], b0v[0]};
        f32x4 a1 = {b0v[1], b0v[1], b0v[1], b0v[1]};
        #pragma unroll
        for (int s = 0; s < 4; ++s) {
          bf16x8 xa;
          const int k0 = s * 32 + kc * 8;
          if (k0 + 8 <= Ee) {           // s<3: always fully in-bounds
            if constexpr (ISBF) {
              xa = *(const bf16x8*)((const __bf16*)emb + tok * Ee + k0);
            } else {
              f32x4 lo = *(const f32x4*)((const float*)emb + tok * Ee + k0);
              f32x4 hi = *(const f32x4*)((const float*)emb + tok * Ee + k0 + 4);
              #pragma unroll
              for (int j = 0; j < 4; ++j) { xa[j] = (__bf16)lo[j]; xa[4 + j] = (__bf16)hi[j]; }
            }
          } else {                      // s==3: partial (k>=100 zero-padded)
            #pragma unroll
            for (int j = 0; j < 8; ++j) {
              int k = k0 + j;
              xa[j] = (k < Ee) ? (__bf16)ldf<ISBF>(emb, tok * Ee + k) : (__bf16)0.f;
            }
          }
          a0 = MFMA16(xa, fX[0][s], a0);
          a1 = MFMA16(xa, fX[1][s], a1);
        }
        // pack 8 slots (wv&1)*8 + e*4 + i and store one b128
        bf16x8 pk;
        #pragma unroll
        for (int i = 0; i < 4; ++i) { pk[i] = (__bf16)a0[i]; pk[4 + i] = (__bf16)a1[i]; }
        const int t_l = T0 + mt * 2 + (kc >> 1);   // plane this lane produced
        *(bf16x8*)(Ustore + (size_t)(t_l * 256 + rb) * 2048) = pk;
      }
    }
  }

  // persistent weight B-frags: 2 tiles x 3 matrices x 8 chunks = 192 regs
  bf16x8 fWh0[2][8], fWx1f[2][8], fWh1[2][8];
  float b1v[2];
  #pragma unroll
  for (int e = 0; e < 2; ++e) {
    const int col = wv * 32 + e * 16 + m;
    b1v[e] = ldf<ISBF>(bias, Uu + col);
    #pragma unroll
    for (int s = 0; s < 8; ++s) {
      const int kb = s * 32 + kc * 8;
      bf16x8 t0, t1, t2;
      #pragma unroll
      for (int j = 0; j < 8; ++j) {
        t0[j] = (__bf16)ldf<ISBF>(Wh,  (kb + j) * Uu + col);
        t1[j] = (__bf16)ldf<ISBF>(Wx1, (kb + j) * Uu + col);
        t2[j] = (__bf16)ldf<ISBF>(Wh,  Uu * Uu + (kb + j) * Uu + col);
      }
      fWh0[e][s] = t0; fWx1f[e][s] = t1; fWh1[e][s] = t2;
    }
  }
  #pragma unroll
  for (int e = 0; e < 2; ++e) {
    #pragma unroll
    for (int s = 0; s < 8; ++s) {
      PIN8(fWh0[e][s]); PIN8(fWx1f[e][s]); PIN8(fWh1[e][s]);
    }
  }

  // u fetch: lane reads tid32 = (wv>>1)*32 + (kc&1)*16 + m, slots (wv&1)*8..+7
  const int tid32u = (wv >> 1) * 32 + ((kc & 1) * 16) + m;
  const __bf16* Ubase = U + (size_t)tid32u * 16 + (wv & 1) * 8 + (size_t)rb * 2048;

  const int kc2 = m >> 3, j2 = m & 7, rb2 = (lane >> 4) * 4;  // write decomp (lane<32)

  __syncthreads();   // drains prologue U stores (vmcnt) + h-stage ds writes

  bf16x8 u0 = *(const bf16x8*)(Ubase);   // u(0) — after barrier: U is visible

  // ---- prologue: h0_new(0) = tanh(u(0) + h0_init@Wh0) -> s_h0[1] ----
  {
    f32x4 d0, d1;
    const __bf16* hb = s_h0 + au;
    d0 = (f32x4){(float)u0[0], (float)u0[1], (float)u0[2], (float)u0[3]};
    d1 = (f32x4){(float)u0[4], (float)u0[5], (float)u0[6], (float)u0[7]};
    #pragma unroll
    for (int s = 0; s < 8; ++s) {
      bf16x8 a = *(const bf16x8*)(hb + s * HCH);
      d0 = MFMA16(a, fWh0[0][s], d0);
      d1 = MFMA16(a, fWh0[1][s], d1);
    }
    u0 = *(const bf16x8*)(Ubase + (size_t)1 * 256 * 2048);  // prefetch u(1)
    if (lane < 32) {
      #pragma unroll
      for (int e = 0; e < 2; ++e) {
        __bf16* wp = s_h0 + HB + wv * HCH + ((e * 2 + kc2) * 8 + rb2) * 8 + j2;
        f32x4& dd = e ? d1 : d0;
        #pragma unroll
        for (int ii = 0; ii < 4; ++ii)
          wp[ii * 8] = (__bf16)fast_tanh(dd[ii]);
      }
    }
    barrier_lds();
  }

  for (int t = 0; t < Tt; ++t) {
    const int p = t & 1, pn = p ^ 1;
    int tf = (t + 2 < Tt) ? t + 2 : Tt - 1;
    bf16x8 un = *(const bf16x8*)(Ubase + (size_t)tf * 256 * 2048);

    // 6 chains: B=h0n@Wx1, C=h1@Wh1 (sum -> h1_new), D=u+h0n@Wh0 (-> h0_next)
    f32x4 cB0 = {0.f,0.f,0.f,0.f}, cB1 = {0.f,0.f,0.f,0.f};
    f32x4 cC0 = {0.f,0.f,0.f,0.f}, cC1 = {0.f,0.f,0.f,0.f};
    f32x4 cD0 = {(float)u0[0], (float)u0[1], (float)u0[2], (float)u0[3]};
    f32x4 cD1 = {(float)u0[4], (float)u0[5], (float)u0[6], (float)u0[7]};
    {
      const __bf16* h0b = s_h0 + pn * HB + au;   // h0_new(t)
      const __bf16* h1b = s_h1 + p * HB + au;    // h1(t)
      #pragma unroll
      for (int s = 0; s < 8; ++s) {
        bf16x8 a0 = *(const bf16x8*)(h0b + s * HCH);
        bf16x8 a1 = *(const bf16x8*)(h1b + s * HCH);
        cB0 = MFMA16(a0, fWx1f[0][s], cB0);
        cB1 = MFMA16(a0, fWx1f[1][s], cB1);
        cD0 = MFMA16(a0, fWh0[0][s], cD0);
        cD1 = MFMA16(a0, fWh0[1][s], cD1);
        cC0 = MFMA16(a1, fWh1[0][s], cC0);
        cC1 = MFMA16(a1, fWh1[1][s], cC1);
      }
    }
    if (lane < 32) {
      #pragma unroll
      for (int e = 0; e < 2; ++e) {
        const int toff = wv * HCH + ((e * 2 + kc2) * 8 + rb2) * 8 + j2;
        __bf16* wp1 = s_h1 + pn * HB + toff;     // h1_new(t)
        __bf16* wp0 = s_h0 + p * HB + toff;      // h0_new(t+1)
        f32x4 hb1, hd0;
        if (e) { hb1 = cB1 + cC1; hd0 = cD1; } else { hb1 = cB0 + cC0; hd0 = cD0; }
        #pragma unroll
        for (int ii = 0; ii < 4; ++ii) {
          wp1[ii * 8] = (__bf16)fast_tanh(hb1[ii] + b1v[e]);
          wp0[ii * 8] = (__bf16)fast_tanh(hd0[ii]);
        }
      }
    }
    u0 = un;
    barrier_lds();
  }

  // ---- epilogue: sigmoid(h1_new(79) @ Wo + bo); lives in s_h1[0] ----
  if (tid < 256) {
    const int r = tid >> 5, q = tid & 31;
    const __bf16* hp = s_h1 + (q >> 2) * HCH + ((q & 3) * 8 + r) * 8;
    bf16x8 hv = *(const bf16x8*)hp;
    float part = 0.f;
    #pragma unroll
    for (int j = 0; j < 8; ++j) part += (float)hv[j] * ldf<ISBF>(Wo, q * 8 + j);
    #pragma unroll
    for (int o = 16; o >= 1; o >>= 1) part += __shfl_down(part, o, 32);
    if (q == 0) {
      float z = part + ldf<ISBF>(bo, 0);
      float sg = 1.f / (1.f + __expf(-z));
      if constexpr (ISBF) ((__bf16*)out)[b0 + r] = (__bf16)sg;
      else                ((float*)out)[b0 + r]  = sg;
    }
  }
}

extern "C" void kernel_launch(void* const* d_in, const int* in_sizes, int n_in,
                              void* d_out, int out_size, void* d_ws, size_t ws_size,
                              hipStream_t stream) {
  const int*  tokens = (const int*)d_in[0];
  const void* emb = d_in[1];
  const void* Wx0 = d_in[2];
  const void* Wx1 = d_in[3];
  const void* Wh  = d_in[4];
  const void* b   = d_in[5];
  const void* h0  = d_in[6];
  const void* Wo  = d_in[7];
  const void* bo  = d_in[8];

  int* flag = (int*)d_ws;
  __bf16* U = (__bf16*)((char*)d_ws + 256);
  const size_t needU = 256 + (size_t)Tt * 256 * 2048 * sizeof(__bf16);  // ~84 MB
  if (ws_size < needU) return;

  detect_kernel<<<1, 64, 0, stream>>>(Wh, flag);
  rnn_kernel<true ><<<dim3(Bb / BM), dim3(RNT), 0, stream>>>(
      tokens, emb, Wx0, Wx1, Wh, b, h0, Wo, bo, U, d_out, flag);
  rnn_kernel<false><<<dim3(Bb / BM), dim3(RNT), 0, stream>>>(
      tokens, emb, Wx0, Wx1, Wh, b, h0, Wo, bo, U, d_out, flag);
}

// Round 11
// 267.353 us; speedup vs baseline: 1.7421x; 1.1467x over previous
//
#include <hip/hip_runtime.h>
#include <hip/hip_bf16.h>

typedef __bf16 bf16x8 __attribute__((ext_vector_type(8)));
typedef __bf16 bf16x4 __attribute__((ext_vector_type(4)));
typedef float  f32x4  __attribute__((ext_vector_type(4)));

#define MFMA16(a,b,c) __builtin_amdgcn_mfma_f32_16x16x32_bf16((a),(b),(c),0,0,0)

// Opaque pin: forces fragments register-resident (not rematerializable).
#define PIN8(v8) do { f32x4 _t = __builtin_bit_cast(f32x4, (v8)); \
                      asm volatile("" : "+v"(_t)); \
                      (v8) = __builtin_bit_cast(bf16x8, _t); } while (0)

// LDS-only barrier: leaves the global u-prefetch vmcnt outstanding.
__device__ __forceinline__ void barrier_lds() {
  asm volatile("s_waitcnt lgkmcnt(0)\n\ts_barrier" ::: "memory");
}

constexpr int Bb = 2048, Tt = 80, Ee = 100, Uu = 256;
constexpr int BM = 8;          // batch rows per block
constexpr int RNT = 512;       // 8 waves
constexpr int HCH = 256;       // elems per k-chunk (32 k x 8 rows)
constexpr int HB = 8 * HCH;    // one h buffer

template<bool ISBF>
__device__ __forceinline__ float ldf(const void* p, int i) {
  if constexpr (ISBF) return (float)((const __bf16*)p)[i];
  else                return ((const float*)p)[i];
}

__device__ __forceinline__ float fast_tanh(float x) {
  float e = __expf(2.f * x);
  return 1.f - 2.f / (e + 1.f);
}

__global__ void detect_kernel(const void* wh, int* flag) {
  __shared__ int cnt;
  if (threadIdx.x == 0) cnt = 0;
  __syncthreads();
  const unsigned short* u = (const unsigned short*)wh;
  int c = 0;
  for (int i = threadIdx.x; i < 256; i += 64) {
    unsigned short h = u[2 * i];
    int ex = (h >> 7) & 0xFF;
    if (ex >= 135 || (ex >= 1 && ex <= 95)) c++;
  }
  atomicAdd(&cnt, c);
  __syncthreads();
  if (threadIdx.x == 0) *flag = (cnt < 64) ? 1 : 0;
}

// ---------------- persistent 2-layer RNN with fused U-production -----------
// Scan = R8/R9 proven structure. NEW: full-wave tail — because lanes m>=8
// broadcast-read rows m-8, C rows 8-15 are bit-exact duplicates of rows 0-7,
// so lanes 32-63 already hold the same accumulators as lanes 0-31. Each
// half-wave writes one col-tile (e = hf) from its OWN registers: tanh/cvt/
// ds_write issues halve, zero shuffles, zero new layout claims.
template<bool ISBF>
__launch_bounds__(RNT, 2)
__global__ void rnn_kernel(const int* __restrict__ tokens,
                           const void* __restrict__ emb,
                           const void* __restrict__ Wx0,
                           const void* __restrict__ Wx1,
                           const void* __restrict__ Wh,
                           const void* __restrict__ bias,
                           const void* __restrict__ h0g,
                           const void* __restrict__ Wo,
                           const void* __restrict__ bo,
                           __bf16* __restrict__ U,
                           void* __restrict__ out,
                           const int* __restrict__ flag) {
  if ((*flag != 0) != ISBF) return;

  __shared__ __align__(16) __bf16 s_h0[2 * HB];
  __shared__ __align__(16) __bf16 s_h1[2 * HB];
  __shared__ int s_tok[BM * Tt];

  const int tid = threadIdx.x, lane = tid & 63, wv = tid >> 6;  // wv 0..7
  const int m = lane & 15, kc = lane >> 4, hf = lane >> 5;
  const int rb = blockIdx.x, b0 = rb * BM;
  const int au = (kc * 8 + (m & 7)) * 8;   // A-read; lanes m>=8 broadcast row m-8

  for (int idx = tid; idx < BM * Tt; idx += RNT)
    s_tok[idx] = tokens[b0 * Tt + idx];

  for (int idx = tid; idx < BM * Uu; idx += RNT) {
    int r = idx >> 8, c = idx & 255;
    int off = (c >> 5) * HCH + (((c >> 3) & 3) * 8 + r) * 8 + (c & 7);
    s_h0[off] = (__bf16)ldf<ISBF>(h0g, (b0 + r) * Uu + c);
    s_h1[off] = (__bf16)ldf<ISBF>(h0g, Bb * Uu + (b0 + r) * Uu + c);
  }
  __syncthreads();

  // ---- fused U-producer (R9-proven) --------------------------------------
  {
    bf16x8 fX[2][4];
    float b0v[2];
    #pragma unroll
    for (int e = 0; e < 2; ++e) {
      const int col = wv * 32 + e * 16 + m;
      b0v[e] = ldf<ISBF>(bias, col);
      #pragma unroll
      for (int s = 0; s < 4; ++s) {
        bf16x8 tr;
        #pragma unroll
        for (int j = 0; j < 8; ++j) {
          int k = s * 32 + kc * 8 + j;
          tr[j] = (k < Ee) ? (__bf16)ldf<ISBF>(Wx0, k * Uu + col) : (__bf16)0.f;
        }
        fX[e][s] = tr;
      }
    }
    const int tid32p = (wv >> 1) * 32 + (kc & 1) * 16 + m;
    __bf16* Ustore = U + (size_t)tid32p * 16 + (wv & 1) * 8;
    for (int tc = 0; tc < 10; ++tc) {
      const int T0 = tc * 8;
      #pragma unroll
      for (int mt = 0; mt < 4; ++mt) {
        const int tok = s_tok[(m & 7) * Tt + T0 + mt * 2 + (m >> 3)];
        f32x4 a0 = {b0v[0], b0v[0], b0v[0], b0v[0]};
        f32x4 a1 = {b0v[1], b0v[1], b0v[1], b0v[1]};
        #pragma unroll
        for (int s = 0; s < 4; ++s) {
          bf16x8 xa;
          const int k0 = s * 32 + kc * 8;
          if (k0 + 8 <= Ee) {
            if constexpr (ISBF) {
              xa = *(const bf16x8*)((const __bf16*)emb + tok * Ee + k0);
            } else {
              f32x4 lo = *(const f32x4*)((const float*)emb + tok * Ee + k0);
              f32x4 hi = *(const f32x4*)((const float*)emb + tok * Ee + k0 + 4);
              #pragma unroll
              for (int j = 0; j < 4; ++j) { xa[j] = (__bf16)lo[j]; xa[4 + j] = (__bf16)hi[j]; }
            }
          } else {
            #pragma unroll
            for (int j = 0; j < 8; ++j) {
              int k = k0 + j;
              xa[j] = (k < Ee) ? (__bf16)ldf<ISBF>(emb, tok * Ee + k) : (__bf16)0.f;
            }
          }
          a0 = MFMA16(xa, fX[0][s], a0);
          a1 = MFMA16(xa, fX[1][s], a1);
        }
        bf16x8 pk;
        #pragma unroll
        for (int i = 0; i < 4; ++i) { pk[i] = (__bf16)a0[i]; pk[4 + i] = (__bf16)a1[i]; }
        const int t_l = T0 + mt * 2 + (kc >> 1);
        *(bf16x8*)(Ustore + (size_t)(t_l * 256 + rb) * 2048) = pk;
      }
    }
  }

  // ---- pinned weight B-frags: 2 tiles x 3 matrices x 8 chunks ------------
  bf16x8 fWh0[2][8], fWx1f[2][8], fWh1[2][8];
  #pragma unroll
  for (int e = 0; e < 2; ++e) {
    const int col = wv * 32 + e * 16 + m;
    #pragma unroll
    for (int s = 0; s < 8; ++s) {
      const int kb = s * 32 + kc * 8;
      bf16x8 t0, t1, t2;
      #pragma unroll
      for (int j = 0; j < 8; ++j) {
        t0[j] = (__bf16)ldf<ISBF>(Wh,  (kb + j) * Uu + col);
        t1[j] = (__bf16)ldf<ISBF>(Wx1, (kb + j) * Uu + col);
        t2[j] = (__bf16)ldf<ISBF>(Wh,  Uu * Uu + (kb + j) * Uu + col);
      }
      fWh0[e][s] = t0; fWx1f[e][s] = t1; fWh1[e][s] = t2;
    }
  }
  #pragma unroll
  for (int e = 0; e < 2; ++e) {
    #pragma unroll
    for (int s = 0; s < 8; ++s) {
      PIN8(fWh0[e][s]); PIN8(fWx1f[e][s]); PIN8(fWh1[e][s]);
    }
  }
  const float b1s = ldf<ISBF>(bias, Uu + wv * 32 + hf * 16 + m);  // this half's tile col

  // u fetch: lane reads tid32 = (wv>>1)*32 + (kc&1)*16 + m, slots (wv&1)*8..+7
  const int tid32u = (wv >> 1) * 32 + ((kc & 1) * 16) + m;
  const __bf16* Ubase = U + (size_t)tid32u * 16 + (wv & 1) * 8 + (size_t)rb * 2048;

  // full-wave write decomp: each half-wave writes tile e = hf, rows rgr+ii
  const int kc2 = m >> 3, j2 = m & 7, rgr = ((lane >> 4) & 1) * 4;
  const int toffw = wv * HCH + ((hf * 2 + kc2) * 8 + rgr) * 8 + j2;

  __syncthreads();   // drain U stores (vmcnt) + LDS staging

  bf16x8 u0 = *(const bf16x8*)(Ubase);   // u(0)

  // ---- prologue: h0_new(0) = tanh(u(0) + h0_init@Wh0) -> s_h0[1] ----
  {
    f32x4 d0 = {(float)u0[0], (float)u0[1], (float)u0[2], (float)u0[3]};
    f32x4 d1 = {(float)u0[4], (float)u0[5], (float)u0[6], (float)u0[7]};
    const __bf16* hb = s_h0 + au;
    #pragma unroll
    for (int s = 0; s < 8; ++s) {
      bf16x8 a = *(const bf16x8*)(hb + s * HCH);
      d0 = MFMA16(a, fWh0[0][s], d0);
      d1 = MFMA16(a, fWh0[1][s], d1);
    }
    u0 = *(const bf16x8*)(Ubase + (size_t)1 * 256 * 2048);  // prefetch u(1)
    __bf16* wp = s_h0 + HB + toffw;
    #pragma unroll
    for (int ii = 0; ii < 4; ++ii) {
      float dd = hf ? d1[ii] : d0[ii];   // upper half holds duplicate rows
      wp[ii * 8] = (__bf16)fast_tanh(dd);
    }
    barrier_lds();
  }

  for (int t = 0; t < Tt; ++t) {
    const int p = t & 1, pn = p ^ 1;
    int tf = (t + 2 < Tt) ? t + 2 : Tt - 1;
    bf16x8 un = *(const bf16x8*)(Ubase + (size_t)tf * 256 * 2048);

    // 6 chains: B=h0n@Wx1, C=h1@Wh1 (sum -> h1_new), D=u+h0n@Wh0 (-> h0_next)
    f32x4 cB0 = {0.f,0.f,0.f,0.f}, cB1 = {0.f,0.f,0.f,0.f};
    f32x4 cC0 = {0.f,0.f,0.f,0.f}, cC1 = {0.f,0.f,0.f,0.f};
    f32x4 cD0 = {(float)u0[0], (float)u0[1], (float)u0[2], (float)u0[3]};
    f32x4 cD1 = {(float)u0[4], (float)u0[5], (float)u0[6], (float)u0[7]};
    {
      const __bf16* h0b = s_h0 + pn * HB + au;   // h0_new(t)
      const __bf16* h1b = s_h1 + p * HB + au;    // h1(t)
      #pragma unroll
      for (int s = 0; s < 8; ++s) {
        bf16x8 a0 = *(const bf16x8*)(h0b + s * HCH);
        bf16x8 a1 = *(const bf16x8*)(h1b + s * HCH);
        cB0 = MFMA16(a0, fWx1f[0][s], cB0);
        cB1 = MFMA16(a0, fWx1f[1][s], cB1);
        cD0 = MFMA16(a0, fWh0[0][s], cD0);
        cD1 = MFMA16(a0, fWh0[1][s], cD1);
        cC0 = MFMA16(a1, fWh1[0][s], cC0);
        cC1 = MFMA16(a1, fWh1[1][s], cC1);
      }
    }
    // full-wave tail: half-wave hf writes tile e=hf from its own (duplicate)
    // accumulators — tanh/cvt/write issues halved vs masked lane<32 version.
    {
      __bf16* wp1 = s_h1 + pn * HB + toffw;      // h1_new(t)
      __bf16* wp0 = s_h0 + p * HB + toffw;       // h0_new(t+1)
      #pragma unroll
      for (int ii = 0; ii < 4; ++ii) {
        float v1 = hf ? (cB1[ii] + cC1[ii]) : (cB0[ii] + cC0[ii]);
        float v0 = hf ? cD1[ii] : cD0[ii];
        wp1[ii * 8] = (__bf16)fast_tanh(v1 + b1s);
        wp0[ii * 8] = (__bf16)fast_tanh(v0);
      }
    }
    u0 = un;
    barrier_lds();
  }

  // ---- epilogue: sigmoid(h1_new(79) @ Wo + bo); lives in s_h1[0] ----
  if (tid < 256) {
    const int r = tid >> 5, q = tid & 31;
    const __bf16* hp = s_h1 + (q >> 2) * HCH + ((q & 3) * 8 + r) * 8;
    bf16x8 hv = *(const bf16x8*)hp;
    float part = 0.f;
    #pragma unroll
    for (int j = 0; j < 8; ++j) part += (float)hv[j] * ldf<ISBF>(Wo, q * 8 + j);
    #pragma unroll
    for (int o = 16; o >= 1; o >>= 1) part += __shfl_down(part, o, 32);
    if (q == 0) {
      float z = part + ldf<ISBF>(bo, 0);
      float sg = 1.f / (1.f + __expf(-z));
      if constexpr (ISBF) ((__bf16*)out)[b0 + r] = (__bf16)sg;
      else                ((float*)out)[b0 + r]  = sg;
    }
  }
}

extern "C" void kernel_launch(void* const* d_in, const int* in_sizes, int n_in,
                              void* d_out, int out_size, void* d_ws, size_t ws_size,
                              hipStream_t stream) {
  const int*  tokens = (const int*)d_in[0];
  const void* emb = d_in[1];
  const void* Wx0 = d_in[2];
  const void* Wx1 = d_in[3];
  const void* Wh  = d_in[4];
  const void* b   = d_in[5];
  const void* h0  = d_in[6];
  const void* Wo  = d_in[7];
  const void* bo  = d_in[8];

  int* flag = (int*)d_ws;
  __bf16* U = (__bf16*)((char*)d_ws + 256);
  const size_t needU = 256 + (size_t)Tt * 256 * 2048 * sizeof(__bf16);  // ~84 MB
  if (ws_size < needU) return;

  detect_kernel<<<1, 64, 0, stream>>>(Wh, flag);
  rnn_kernel<true ><<<dim3(Bb / BM), dim3(RNT), 0, stream>>>(
      tokens, emb, Wx0, Wx1, Wh, b, h0, Wo, bo, U, d_out, flag);
  rnn_kernel<false><<<dim3(Bb / BM), dim3(RNT), 0, stream>>>(
      tokens, emb, Wx0, Wx1, Wh, b, h0, Wo, bo, U, d_out, flag);
}

// Round 12
// 240.966 us; speedup vs baseline: 1.9329x; 1.1095x over previous
//
#include <hip/hip_runtime.h>
#include <hip/hip_bf16.h>

typedef __bf16 bf16x8 __attribute__((ext_vector_type(8)));
typedef __bf16 bf16x4 __attribute__((ext_vector_type(4)));
typedef float  f32x4  __attribute__((ext_vector_type(4)));

#define MFMA16(a,b,c) __builtin_amdgcn_mfma_f32_16x16x32_bf16((a),(b),(c),0,0,0)

// Opaque pin: forces fragments register-resident (not rematerializable).
#define PIN8(v8) do { f32x4 _t = __builtin_bit_cast(f32x4, (v8)); \
                      asm volatile("" : "+v"(_t)); \
                      (v8) = __builtin_bit_cast(bf16x8, _t); } while (0)

// LDS-only barrier: leaves the global u-prefetch vmcnt outstanding.
__device__ __forceinline__ void barrier_lds() {
  asm volatile("s_waitcnt lgkmcnt(0)\n\ts_barrier" ::: "memory");
}

constexpr int Bb = 2048, Tt = 80, Ee = 100, Uu = 256;
constexpr int BM = 8;          // batch rows per block
constexpr int RNT = 512;       // 8 waves
constexpr int HCH = 256;       // elems per k-chunk (32 k x 8 rows)
constexpr int HB = 8 * HCH;    // one h buffer

template<bool ISBF>
__device__ __forceinline__ float ldf(const void* p, int i) {
  if constexpr (ISBF) return (float)((const __bf16*)p)[i];
  else                return ((const float*)p)[i];
}

__device__ __forceinline__ float fast_tanh(float x) {
  float e = __expf(2.f * x);
  return 1.f - 2.f / (e + 1.f);
}

// In-kernel dtype detect: f32 storage -> low 16-bit halves decode as bf16
// with wild exponents ~84% of the time; genuine bf16 N(0,1/16) never does.
// All lanes/waves compute identically from Wh's first 256 values; no LDS.
__device__ __forceinline__ bool detect_bf16(const void* wh) {
  const unsigned short* u = (const unsigned short*)wh;
  int c = 0;
  const int lane = threadIdx.x & 63;
  #pragma unroll
  for (int r = 0; r < 4; ++r) {
    unsigned short h = u[2 * (lane + 64 * r)];
    int ex = (h >> 7) & 0xFF;
    if (ex >= 135 || (ex >= 1 && ex <= 95)) c++;
  }
  #pragma unroll
  for (int o = 32; o >= 1; o >>= 1) c += __shfl_down(c, o, 64);
  return __shfl(c, 0, 64) < 64;
}

// ---------------- persistent 2-layer RNN with fused U-production -----------
// Scan = R11 proven structure (duplicate-row full-wave tail). NEW vs R11:
// (1) in-kernel detect (no detect dispatch, no d_ws flag round-trip);
// (2) producer pipelining: all 16 emb gathers per tc-group hoisted into
//     registers before the MFMA chain (same values, same FMA order).
template<bool ISBF>
__launch_bounds__(RNT, 2)
__global__ void rnn_kernel(const int* __restrict__ tokens,
                           const void* __restrict__ emb,
                           const void* __restrict__ Wx0,
                           const void* __restrict__ Wx1,
                           const void* __restrict__ Wh,
                           const void* __restrict__ bias,
                           const void* __restrict__ h0g,
                           const void* __restrict__ Wo,
                           const void* __restrict__ bo,
                           __bf16* __restrict__ U,
                           void* __restrict__ out) {
  if (detect_bf16(Wh) != ISBF) return;   // wrong-dtype instantiation exits

  __shared__ __align__(16) __bf16 s_h0[2 * HB];
  __shared__ __align__(16) __bf16 s_h1[2 * HB];
  __shared__ int s_tok[BM * Tt];

  const int tid = threadIdx.x, lane = tid & 63, wv = tid >> 6;  // wv 0..7
  const int m = lane & 15, kc = lane >> 4, hf = lane >> 5;
  const int rb = blockIdx.x, b0 = rb * BM;
  const int au = (kc * 8 + (m & 7)) * 8;   // A-read; lanes m>=8 broadcast row m-8

  for (int idx = tid; idx < BM * Tt; idx += RNT)
    s_tok[idx] = tokens[b0 * Tt + idx];

  for (int idx = tid; idx < BM * Uu; idx += RNT) {
    int r = idx >> 8, c = idx & 255;
    int off = (c >> 5) * HCH + (((c >> 3) & 3) * 8 + r) * 8 + (c & 7);
    s_h0[off] = (__bf16)ldf<ISBF>(h0g, (b0 + r) * Uu + c);
    s_h1[off] = (__bf16)ldf<ISBF>(h0g, Bb * Uu + (b0 + r) * Uu + c);
  }
  __syncthreads();

  // ---- fused U-producer (R9-proven mapping; pipelined gathers) -----------
  {
    bf16x8 fX[2][4];
    float b0v[2];
    #pragma unroll
    for (int e = 0; e < 2; ++e) {
      const int col = wv * 32 + e * 16 + m;
      b0v[e] = ldf<ISBF>(bias, col);
      #pragma unroll
      for (int s = 0; s < 4; ++s) {
        bf16x8 tr;
        #pragma unroll
        for (int j = 0; j < 8; ++j) {
          int k = s * 32 + kc * 8 + j;
          tr[j] = (k < Ee) ? (__bf16)ldf<ISBF>(Wx0, k * Uu + col) : (__bf16)0.f;
        }
        fX[e][s] = tr;
      }
    }
    const int tid32p = (wv >> 1) * 32 + (kc & 1) * 16 + m;
    __bf16* Ustore = U + (size_t)tid32p * 16 + (wv & 1) * 8;
    for (int tc = 0; tc < 10; ++tc) {
      const int T0 = tc * 8;
      // phase 1: all 16 gathers in flight (no MFMA between them)
      bf16x8 xa[4][4];
      #pragma unroll
      for (int mt = 0; mt < 4; ++mt) {
        const int tok = s_tok[(m & 7) * Tt + T0 + mt * 2 + (m >> 3)];
        #pragma unroll
        for (int s = 0; s < 4; ++s) {
          const int k0 = s * 32 + kc * 8;
          if (k0 + 8 <= Ee) {
            if constexpr (ISBF) {
              xa[mt][s] = *(const bf16x8*)((const __bf16*)emb + tok * Ee + k0);
            } else {
              f32x4 lo = *(const f32x4*)((const float*)emb + tok * Ee + k0);
              f32x4 hi = *(const f32x4*)((const float*)emb + tok * Ee + k0 + 4);
              #pragma unroll
              for (int j = 0; j < 4; ++j) { xa[mt][s][j] = (__bf16)lo[j]; xa[mt][s][4 + j] = (__bf16)hi[j]; }
            }
          } else if (k0 < Ee) {       // k0==96: one vector load of k=96..99
            if constexpr (ISBF) {
              bf16x4 t4 = *(const bf16x4*)((const __bf16*)emb + tok * Ee + k0);
              #pragma unroll
              for (int j = 0; j < 4; ++j) { xa[mt][s][j] = t4[j]; xa[mt][s][4 + j] = (__bf16)0.f; }
            } else {
              f32x4 t4 = *(const f32x4*)((const float*)emb + tok * Ee + k0);
              #pragma unroll
              for (int j = 0; j < 4; ++j) { xa[mt][s][j] = (__bf16)t4[j]; xa[mt][s][4 + j] = (__bf16)0.f; }
            }
          } else {                    // k0 >= 100 (kc-dependent): all zero
            #pragma unroll
            for (int j = 0; j < 8; ++j) xa[mt][s][j] = (__bf16)0.f;
          }
        }
      }
      // phase 2: MFMA chains + packed stores
      #pragma unroll
      for (int mt = 0; mt < 4; ++mt) {
        f32x4 a0 = {b0v[0], b0v[0], b0v[0], b0v[0]};
        f32x4 a1 = {b0v[1], b0v[1], b0v[1], b0v[1]};
        #pragma unroll
        for (int s = 0; s < 4; ++s) {
          a0 = MFMA16(xa[mt][s], fX[0][s], a0);
          a1 = MFMA16(xa[mt][s], fX[1][s], a1);
        }
        bf16x8 pk;
        #pragma unroll
        for (int i = 0; i < 4; ++i) { pk[i] = (__bf16)a0[i]; pk[4 + i] = (__bf16)a1[i]; }
        const int t_l = T0 + mt * 2 + (kc >> 1);
        *(bf16x8*)(Ustore + (size_t)(t_l * 256 + rb) * 2048) = pk;
      }
    }
  }

  // ---- pinned weight B-frags: 2 tiles x 3 matrices x 8 chunks ------------
  bf16x8 fWh0[2][8], fWx1f[2][8], fWh1[2][8];
  #pragma unroll
  for (int e = 0; e < 2; ++e) {
    const int col = wv * 32 + e * 16 + m;
    #pragma unroll
    for (int s = 0; s < 8; ++s) {
      const int kb = s * 32 + kc * 8;
      bf16x8 t0, t1, t2;
      #pragma unroll
      for (int j = 0; j < 8; ++j) {
        t0[j] = (__bf16)ldf<ISBF>(Wh,  (kb + j) * Uu + col);
        t1[j] = (__bf16)ldf<ISBF>(Wx1, (kb + j) * Uu + col);
        t2[j] = (__bf16)ldf<ISBF>(Wh,  Uu * Uu + (kb + j) * Uu + col);
      }
      fWh0[e][s] = t0; fWx1f[e][s] = t1; fWh1[e][s] = t2;
    }
  }
  #pragma unroll
  for (int e = 0; e < 2; ++e) {
    #pragma unroll
    for (int s = 0; s < 8; ++s) {
      PIN8(fWh0[e][s]); PIN8(fWx1f[e][s]); PIN8(fWh1[e][s]);
    }
  }
  const float b1s = ldf<ISBF>(bias, Uu + wv * 32 + hf * 16 + m);  // this half's tile col

  // u fetch: lane reads tid32 = (wv>>1)*32 + (kc&1)*16 + m, slots (wv&1)*8..+7
  const int tid32u = (wv >> 1) * 32 + ((kc & 1) * 16) + m;
  const __bf16* Ubase = U + (size_t)tid32u * 16 + (wv & 1) * 8 + (size_t)rb * 2048;

  // full-wave write decomp: each half-wave writes tile e = hf, rows rgr+ii
  const int kc2 = m >> 3, j2 = m & 7, rgr = ((lane >> 4) & 1) * 4;
  const int toffw = wv * HCH + ((hf * 2 + kc2) * 8 + rgr) * 8 + j2;

  __syncthreads();   // drain U stores (vmcnt) + LDS staging

  bf16x8 u0 = *(const bf16x8*)(Ubase);   // u(0)

  // ---- prologue: h0_new(0) = tanh(u(0) + h0_init@Wh0) -> s_h0[1] ----
  {
    f32x4 d0 = {(float)u0[0], (float)u0[1], (float)u0[2], (float)u0[3]};
    f32x4 d1 = {(float)u0[4], (float)u0[5], (float)u0[6], (float)u0[7]};
    const __bf16* hb = s_h0 + au;
    #pragma unroll
    for (int s = 0; s < 8; ++s) {
      bf16x8 a = *(const bf16x8*)(hb + s * HCH);
      d0 = MFMA16(a, fWh0[0][s], d0);
      d1 = MFMA16(a, fWh0[1][s], d1);
    }
    u0 = *(const bf16x8*)(Ubase + (size_t)1 * 256 * 2048);  // prefetch u(1)
    __bf16* wp = s_h0 + HB + toffw;
    #pragma unroll
    for (int ii = 0; ii < 4; ++ii) {
      float dd = hf ? d1[ii] : d0[ii];   // upper half holds duplicate rows
      wp[ii * 8] = (__bf16)fast_tanh(dd);
    }
    barrier_lds();
  }

  for (int t = 0; t < Tt; ++t) {
    const int p = t & 1, pn = p ^ 1;
    int tf = (t + 2 < Tt) ? t + 2 : Tt - 1;
    bf16x8 un = *(const bf16x8*)(Ubase + (size_t)tf * 256 * 2048);

    // 6 chains: B=h0n@Wx1, C=h1@Wh1 (sum -> h1_new), D=u+h0n@Wh0 (-> h0_next)
    f32x4 cB0 = {0.f,0.f,0.f,0.f}, cB1 = {0.f,0.f,0.f,0.f};
    f32x4 cC0 = {0.f,0.f,0.f,0.f}, cC1 = {0.f,0.f,0.f,0.f};
    f32x4 cD0 = {(float)u0[0], (float)u0[1], (float)u0[2], (float)u0[3]};
    f32x4 cD1 = {(float)u0[4], (float)u0[5], (float)u0[6], (float)u0[7]};
    {
      const __bf16* h0b = s_h0 + pn * HB + au;   // h0_new(t)
      const __bf16* h1b = s_h1 + p * HB + au;    // h1(t)
      #pragma unroll
      for (int s = 0; s < 8; ++s) {
        bf16x8 a0 = *(const bf16x8*)(h0b + s * HCH);
        bf16x8 a1 = *(const bf16x8*)(h1b + s * HCH);
        cB0 = MFMA16(a0, fWx1f[0][s], cB0);
        cB1 = MFMA16(a0, fWx1f[1][s], cB1);
        cD0 = MFMA16(a0, fWh0[0][s], cD0);
        cD1 = MFMA16(a0, fWh0[1][s], cD1);
        cC0 = MFMA16(a1, fWh1[0][s], cC0);
        cC1 = MFMA16(a1, fWh1[1][s], cC1);
      }
    }
    // full-wave tail: half-wave hf writes tile e=hf from its own (duplicate)
    // accumulators — tanh/cvt/write issues halved vs masked lane<32 version.
    {
      __bf16* wp1 = s_h1 + pn * HB + toffw;      // h1_new(t)
      __bf16* wp0 = s_h0 + p * HB + toffw;       // h0_new(t+1)
      #pragma unroll
      for (int ii = 0; ii < 4; ++ii) {
        float v1 = hf ? (cB1[ii] + cC1[ii]) : (cB0[ii] + cC0[ii]);
        float v0 = hf ? cD1[ii] : cD0[ii];
        wp1[ii * 8] = (__bf16)fast_tanh(v1 + b1s);
        wp0[ii * 8] = (__bf16)fast_tanh(v0);
      }
    }
    u0 = un;
    barrier_lds();
  }

  // ---- epilogue: sigmoid(h1_new(79) @ Wo + bo); lives in s_h1[0] ----
  if (tid < 256) {
    const int r = tid >> 5, q = tid & 31;
    const __bf16* hp = s_h1 + (q >> 2) * HCH + ((q & 3) * 8 + r) * 8;
    bf16x8 hv = *(const bf16x8*)hp;
    float part = 0.f;
    #pragma unroll
    for (int j = 0; j < 8; ++j) part += (float)hv[j] * ldf<ISBF>(Wo, q * 8 + j);
    #pragma unroll
    for (int o = 16; o >= 1; o >>= 1) part += __shfl_down(part, o, 32);
    if (q == 0) {
      float z = part + ldf<ISBF>(bo, 0);
      float sg = 1.f / (1.f + __expf(-z));
      if constexpr (ISBF) ((__bf16*)out)[b0 + r] = (__bf16)sg;
      else                ((float*)out)[b0 + r]  = sg;
    }
  }
}

extern "C" void kernel_launch(void* const* d_in, const int* in_sizes, int n_in,
                              void* d_out, int out_size, void* d_ws, size_t ws_size,
                              hipStream_t stream) {
  const int*  tokens = (const int*)d_in[0];
  const void* emb = d_in[1];
  const void* Wx0 = d_in[2];
  const void* Wx1 = d_in[3];
  const void* Wh  = d_in[4];
  const void* b   = d_in[5];
  const void* h0  = d_in[6];
  const void* Wo  = d_in[7];
  const void* bo  = d_in[8];

  __bf16* U = (__bf16*)((char*)d_ws + 256);
  const size_t needU = 256 + (size_t)Tt * 256 * 2048 * sizeof(__bf16);  // ~84 MB
  if (ws_size < needU) return;

  rnn_kernel<true ><<<dim3(Bb / BM), dim3(RNT), 0, stream>>>(
      tokens, emb, Wx0, Wx1, Wh, b, h0, Wo, bo, U, d_out);
  rnn_kernel<false><<<dim3(Bb / BM), dim3(RNT), 0, stream>>>(
      tokens, emb, Wx0, Wx1, Wh, b, h0, Wo, bo, U, d_out);
}